// Round 11
// baseline (38.920 us; speedup 1.0000x reference)
//
#include <hip/hip_runtime.h>

// Problem constants (from reference): H=64, EH=128, B=512, T=512
#define B_  512
#define T_  512
#define H_  64
#define EH_ 128   // 2*H
#define NW  8     // waves per block (512 threads)
#define NG  32    // partial groups per block (NW * 4)

__device__ __forceinline__ float sigm(float x) { return 1.0f / (1.0f + __expf(-x)); }

__device__ __forceinline__ float dot4(const float4& a, const float4& b) {
  return a.x * b.x + a.y * b.y + a.z * b.z + a.w * b.w;
}
__device__ __forceinline__ float dot8(const float4& a1, const float4& a2,
                                      const float4& b1, const float4& b2) {
  return dot4(a1, b1) + dot4(a2, b2);
}

// Nontemporal float4 load: enc is streamed once per dispatch (no reuse), so
// skip cache-line allocation (nt) to cut L2 pollution. The builtin requires a
// native vector type, not HIP_vector_type.
typedef float nativef4 __attribute__((ext_vector_type(4)));
__device__ __forceinline__ float4 ldnt(const float* p) {
  nativef4 v = __builtin_nontemporal_load((const nativef4*)p);
  return make_float4(v.x, v.y, v.z, v.w);
}

__global__ __launch_bounds__(512, 4)
void attn_decoder_fused(const float* __restrict__ h0, const float* __restrict__ c0,
                        const float* __restrict__ enc,
                        const float* __restrict__ Wa,  const float* __restrict__ ba,
                        const float* __restrict__ Wc,  const float* __restrict__ bc,
                        const float* __restrict__ wif, const float* __restrict__ whf,
                        const float* __restrict__ bif, const float* __restrict__ bhf,
                        const float* __restrict__ wir, const float* __restrict__ whr,
                        const float* __restrict__ bir, const float* __restrict__ bhr,
                        const int* __restrict__ dip,
                        float* __restrict__ out)
{
  const int b    = blockIdx.x;
  const int tid  = threadIdx.x;
  const int lane = tid & 63;
  const int wv   = tid >> 6;    // 0..7
  const int grp  = lane >> 4;   // 0..3  (row within quad)
  const int gl   = lane & 15;   // 0..15 (column group: 16 lanes per row)

  __shared__ float s_l[NG];
  __shared__ float s_acc[NG][EH_];      // 16 KB
  __shared__ float s_cat[2 * EH_];      // [enc[b,di,:], attn_applied]
  __shared__ float s_comb[H_];
  __shared__ float s_h0[2 * H_];
  __shared__ float s_gates[2][4 * H_];

  const float* encb = enc + (size_t)b * T_ * EH_;

  // this lane's 8 attention-weight columns (dec-hidden half of W_attn + bias
  // cancel in the softmax -> never computed)
  const float4 w1 = *(const float4*)(&Wa[4 * gl]);
  const float4 w2 = *(const float4*)(&Wa[64 + 4 * gl]);

  float  l = 0.0f;
  float4 acc1 = {0.f, 0.f, 0.f, 0.f}, acc2 = {0.f, 0.f, 0.f, 0.f};

  const float* rb = encb + (size_t)(wv * 64 + grp) * EH_ + 4 * gl;

  // ---- attention: quad geometry, additive (no-max) softmax, NT loads ----
#pragma unroll 1
  for (int it = 0; it < 4; ++it) {
    const float* p0 = rb + (size_t)(it * 16) * EH_;
    float4 eA1 = ldnt(p0);
    float4 eA2 = ldnt(p0 + 64);
    float4 eB1 = ldnt(p0 + 4 * EH_);
    float4 eB2 = ldnt(p0 + 4 * EH_ + 64);
    float4 eC1 = ldnt(p0 + 8 * EH_);
    float4 eC2 = ldnt(p0 + 8 * EH_ + 64);
    float4 eD1 = ldnt(p0 + 12 * EH_);
    float4 eD2 = ldnt(p0 + 12 * EH_ + 64);

    float sA = dot8(eA1, eA2, w1, w2);
    float sB = dot8(eB1, eB2, w1, w2);
    float sC = dot8(eC1, eC2, w1, w2);
    float sD = dot8(eD1, eD2, w1, w2);
#pragma unroll
    for (int off = 8; off; off >>= 1) {
      sA += __shfl_xor(sA, off, 64);
      sB += __shfl_xor(sB, off, 64);
      sC += __shfl_xor(sC, off, 64);
      sD += __shfl_xor(sD, off, 64);
    }
    float pA = __expf(sA), pB = __expf(sB);
    float pC = __expf(sC), pD = __expf(sD);
    l += pA + pB + pC + pD;
    acc1.x += pA * eA1.x + pB * eB1.x + pC * eC1.x + pD * eD1.x;
    acc1.y += pA * eA1.y + pB * eB1.y + pC * eC1.y + pD * eD1.y;
    acc1.z += pA * eA1.z + pB * eB1.z + pC * eC1.z + pD * eD1.z;
    acc1.w += pA * eA1.w + pB * eB1.w + pC * eC1.w + pD * eD1.w;
    acc2.x += pA * eA2.x + pB * eB2.x + pC * eC2.x + pD * eD2.x;
    acc2.y += pA * eA2.y + pB * eB2.y + pC * eC2.y + pD * eD2.y;
    acc2.z += pA * eA2.z + pB * eB2.z + pC * eC2.z + pD * eD2.z;
    acc2.w += pA * eA2.w + pB * eB2.w + pC * eC2.w + pD * eD2.w;
  }

  const int g = wv * 4 + grp;   // partial-group id 0..31
  *(float4*)(&s_acc[g][4 * gl])      = acc1;
  *(float4*)(&s_acc[g][64 + 4 * gl]) = acc2;
  if (gl == 0) s_l[g] = l;
  __syncthreads();

  const int di = dip[0];

  // ---- merge 32 partial states (plain sums); build cat + h0 in LDS ----
  if (tid < EH_) {
    float L = 0.0f, a = 0.0f;
#pragma unroll
    for (int w = 0; w < NG; ++w) { L += s_l[w]; a += s_acc[w][tid]; }
    s_cat[EH_ + tid] = a / L;                        // attn_applied
    s_cat[tid]       = encb[(size_t)di * EH_ + tid]; // enc[b, di, :]
  } else if (tid < 2 * EH_) {
    int j = tid - EH_;
    s_h0[j] = h0[(j >> 6) * B_ * H_ + b * H_ + (j & 63)];
  }
  __syncthreads();

  // ---- comb = relu(cat @ Wc^T + bc): coalesced, one Wc row per wave-instr ----
  {
    float4 c4 = *(const float4*)(&s_cat[4 * lane]);
#pragma unroll
    for (int batch = 0; batch < 2; ++batch) {
      const int r0 = wv * 8 + batch * 4;
      float sA = dot4(*(const float4*)(Wc + (r0 + 0) * 256 + 4 * lane), c4);
      float sB = dot4(*(const float4*)(Wc + (r0 + 1) * 256 + 4 * lane), c4);
      float sC = dot4(*(const float4*)(Wc + (r0 + 2) * 256 + 4 * lane), c4);
      float sD = dot4(*(const float4*)(Wc + (r0 + 3) * 256 + 4 * lane), c4);
#pragma unroll
      for (int off = 32; off; off >>= 1) {
        sA += __shfl_xor(sA, off, 64);
        sB += __shfl_xor(sB, off, 64);
        sC += __shfl_xor(sC, off, 64);
        sD += __shfl_xor(sD, off, 64);
      }
      if (lane < 4) {
        int r = r0 + lane;
        float v = (lane == 0) ? sA : (lane == 1) ? sB : (lane == 2) ? sC : sD;
        s_comb[r] = fmaxf(v + bc[r], 0.0f);
      }
    }
  }
  __syncthreads();

  // ---- gates: coalesced quad geometry; dir is wave-uniform ----
  {
    const int dir   = wv >> 2;
    const int gbase = (wv & 3) * 64;
    const float* wih = dir ? wir : wif;
    const float* whh = dir ? whr : whf;
    const float* bih = dir ? bir : bif;
    const float* bhh = dir ? bhr : bhf;
    float4 cm4 = *(const float4*)(&s_comb[4 * gl]);
    float4 h4  = *(const float4*)(&s_h0[dir * H_ + 4 * gl]);
#pragma unroll
    for (int batch = 0; batch < 4; ++batch) {
      const int r0 = gbase + batch * 16;   // 16 gate rows this step
      float sA = dot4(*(const float4*)(wih + (r0 +  0 + grp) * H_ + 4 * gl), cm4)
               + dot4(*(const float4*)(whh + (r0 +  0 + grp) * H_ + 4 * gl), h4);
      float sB = dot4(*(const float4*)(wih + (r0 +  4 + grp) * H_ + 4 * gl), cm4)
               + dot4(*(const float4*)(whh + (r0 +  4 + grp) * H_ + 4 * gl), h4);
      float sC = dot4(*(const float4*)(wih + (r0 +  8 + grp) * H_ + 4 * gl), cm4)
               + dot4(*(const float4*)(whh + (r0 +  8 + grp) * H_ + 4 * gl), h4);
      float sD = dot4(*(const float4*)(wih + (r0 + 12 + grp) * H_ + 4 * gl), cm4)
               + dot4(*(const float4*)(whh + (r0 + 12 + grp) * H_ + 4 * gl), h4);
#pragma unroll
      for (int off = 8; off; off >>= 1) {
        sA += __shfl_xor(sA, off, 64);
        sB += __shfl_xor(sB, off, 64);
        sC += __shfl_xor(sC, off, 64);
        sD += __shfl_xor(sD, off, 64);
      }
      if (gl < 4) {   // lane gl writes value gl for its grp
        int gg = r0 + gl * 4 + grp;
        float v = (gl == 0) ? sA : (gl == 1) ? sB : (gl == 2) ? sC : sD;
        s_gates[dir][gg] = v + bih[gg] + bhh[gg];
      }
    }
  }
  __syncthreads();

  // ---- finalize LSTM + write all three outputs ----
  if (tid < 2 * H_) {
    int dir = tid >> 6, j = tid & 63;
    float gi = s_gates[dir][j];
    float gf = s_gates[dir][H_ + j];
    float gg = s_gates[dir][2 * H_ + j];
    float go = s_gates[dir][3 * H_ + j];
    float cp = c0[dir * B_ * H_ + b * H_ + j];
    float cn = sigm(gf) * cp + sigm(gi) * tanhf(gg);
    float hn = sigm(go) * tanhf(cn);
    out[b * 2 * H_ + dir * H_ + j]                    = hn;  // output (b,1,128)
    out[B_ * 2 * H_ + dir * B_ * H_ + b * H_ + j]     = hn;  // h_new (2,b,64)
    out[2 * B_ * 2 * H_ + dir * B_ * H_ + b * H_ + j] = cn;  // c_new (2,b,64)
  }
}

extern "C" void kernel_launch(void* const* d_in, const int* in_sizes, int n_in,
                              void* d_out, int out_size, void* d_ws, size_t ws_size,
                              hipStream_t stream) {
  const float* h0  = (const float*)d_in[0];
  const float* c0  = (const float*)d_in[1];
  const float* enc = (const float*)d_in[2];
  const float* Wa  = (const float*)d_in[3];
  const float* ba  = (const float*)d_in[4];
  const float* Wc  = (const float*)d_in[5];
  const float* bc  = (const float*)d_in[6];
  const float* wif = (const float*)d_in[7];
  const float* whf = (const float*)d_in[8];
  const float* bif = (const float*)d_in[9];
  const float* bhf = (const float*)d_in[10];
  const float* wir = (const float*)d_in[11];
  const float* whr = (const float*)d_in[12];
  const float* bir = (const float*)d_in[13];
  const float* bhr = (const float*)d_in[14];
  const int*   dip = (const int*)d_in[15];
  float* out = (float*)d_out;

  attn_decoder_fused<<<B_, 512, 0, stream>>>(h0, c0, enc, Wa, ba, Wc, bc,
                                             wif, whf, bif, bhf,
                                             wir, whr, bir, bhr, dip, out);
}

// Round 12
// 34.010 us; speedup vs baseline: 1.1443x; 1.1443x over previous
//
#include <hip/hip_runtime.h>

// Problem constants (from reference): H=64, EH=128, B=512, T=512
#define B_  512
#define T_  512
#define H_  64
#define EH_ 128   // 2*H
#define NW  8     // waves per block (512 threads)
#define NG  32    // partial groups per block (NW * 4)

__device__ __forceinline__ float sigm(float x) { return 1.0f / (1.0f + __expf(-x)); }

__device__ __forceinline__ float dot4(const float4& a, const float4& b) {
  return a.x * b.x + a.y * b.y + a.z * b.z + a.w * b.w;
}
__device__ __forceinline__ float dot8(const float4& a1, const float4& a2,
                                      const float4& b1, const float4& b2) {
  return dot4(a1, b1) + dot4(a2, b2);
}

__global__ __launch_bounds__(512, 4)
void attn_decoder_fused(const float* __restrict__ h0, const float* __restrict__ c0,
                        const float* __restrict__ enc,
                        const float* __restrict__ Wa,  const float* __restrict__ ba,
                        const float* __restrict__ Wc,  const float* __restrict__ bc,
                        const float* __restrict__ wif, const float* __restrict__ whf,
                        const float* __restrict__ bif, const float* __restrict__ bhf,
                        const float* __restrict__ wir, const float* __restrict__ whr,
                        const float* __restrict__ bir, const float* __restrict__ bhr,
                        const int* __restrict__ dip,
                        float* __restrict__ out)
{
  const int b    = blockIdx.x;
  const int tid  = threadIdx.x;
  const int lane = tid & 63;
  const int wv   = tid >> 6;    // 0..7
  const int grp  = lane >> 4;   // 0..3  (row within quad)
  const int gl   = lane & 15;   // 0..15 (column group: 16 lanes per row)

  __shared__ float s_l[NG];
  __shared__ float s_acc[NG][EH_];      // 16 KB
  __shared__ float s_cat[2 * EH_];      // [enc[b,di,:], attn_applied]
  __shared__ float s_comb[H_];
  __shared__ float s_h0[2 * H_];
  __shared__ float s_gates[2][4 * H_];

  const float* encb = enc + (size_t)b * T_ * EH_;

  // this lane's 8 attention-weight columns (dec-hidden half of W_attn + bias
  // cancel in the softmax -> never computed)
  const float4 w1 = *(const float4*)(&Wa[4 * gl]);
  const float4 w2 = *(const float4*)(&Wa[64 + 4 * gl]);

  float  l = 0.0f;
  float4 acc1 = {0.f, 0.f, 0.f, 0.f}, acc2 = {0.f, 0.f, 0.f, 0.f};

  const float* rb = encb + (size_t)(wv * 64 + grp) * EH_ + 4 * gl;

  // ---- attention: proven quad geometry, additive (no-max) online softmax ----
#pragma unroll 1
  for (int it = 0; it < 4; ++it) {
    const float* p0 = rb + (size_t)(it * 16) * EH_;
    float4 eA1 = *(const float4*)(p0);
    float4 eA2 = *(const float4*)(p0 + 64);
    float4 eB1 = *(const float4*)(p0 + 4 * EH_);
    float4 eB2 = *(const float4*)(p0 + 4 * EH_ + 64);
    float4 eC1 = *(const float4*)(p0 + 8 * EH_);
    float4 eC2 = *(const float4*)(p0 + 8 * EH_ + 64);
    float4 eD1 = *(const float4*)(p0 + 12 * EH_);
    float4 eD2 = *(const float4*)(p0 + 12 * EH_ + 64);

    float sA = dot8(eA1, eA2, w1, w2);
    float sB = dot8(eB1, eB2, w1, w2);
    float sC = dot8(eC1, eC2, w1, w2);
    float sD = dot8(eD1, eD2, w1, w2);
#pragma unroll
    for (int off = 8; off; off >>= 1) {
      sA += __shfl_xor(sA, off, 64);
      sB += __shfl_xor(sB, off, 64);
      sC += __shfl_xor(sC, off, 64);
      sD += __shfl_xor(sD, off, 64);
    }
    float pA = __expf(sA), pB = __expf(sB);
    float pC = __expf(sC), pD = __expf(sD);
    l += pA + pB + pC + pD;
    acc1.x += pA * eA1.x + pB * eB1.x + pC * eC1.x + pD * eD1.x;
    acc1.y += pA * eA1.y + pB * eB1.y + pC * eC1.y + pD * eD1.y;
    acc1.z += pA * eA1.z + pB * eB1.z + pC * eC1.z + pD * eD1.z;
    acc1.w += pA * eA1.w + pB * eB1.w + pC * eC1.w + pD * eD1.w;
    acc2.x += pA * eA2.x + pB * eB2.x + pC * eC2.x + pD * eD2.x;
    acc2.y += pA * eA2.y + pB * eB2.y + pC * eC2.y + pD * eD2.y;
    acc2.z += pA * eA2.z + pB * eB2.z + pC * eC2.z + pD * eD2.z;
    acc2.w += pA * eA2.w + pB * eB2.w + pC * eC2.w + pD * eD2.w;
  }

  const int g = wv * 4 + grp;   // partial-group id 0..31
  *(float4*)(&s_acc[g][4 * gl])      = acc1;
  *(float4*)(&s_acc[g][64 + 4 * gl]) = acc2;
  if (gl == 0) s_l[g] = l;
  __syncthreads();

  const int di = dip[0];

  // ---- merge 32 partial states (plain sums); build cat + h0 in LDS ----
  if (tid < EH_) {
    float L = 0.0f, a = 0.0f;
#pragma unroll
    for (int w = 0; w < NG; ++w) { L += s_l[w]; a += s_acc[w][tid]; }
    s_cat[EH_ + tid] = a / L;                        // attn_applied
    s_cat[tid]       = encb[(size_t)di * EH_ + tid]; // enc[b, di, :]
  } else if (tid < 2 * EH_) {
    int j = tid - EH_;
    s_h0[j] = h0[(j >> 6) * B_ * H_ + b * H_ + (j & 63)];
  }
  __syncthreads();

  // ---- comb = relu(cat @ Wc^T + bc): coalesced, one Wc row per wave-instr ----
  {
    float4 c4 = *(const float4*)(&s_cat[4 * lane]);
#pragma unroll
    for (int batch = 0; batch < 2; ++batch) {
      const int r0 = wv * 8 + batch * 4;
      float sA = dot4(*(const float4*)(Wc + (r0 + 0) * 256 + 4 * lane), c4);
      float sB = dot4(*(const float4*)(Wc + (r0 + 1) * 256 + 4 * lane), c4);
      float sC = dot4(*(const float4*)(Wc + (r0 + 2) * 256 + 4 * lane), c4);
      float sD = dot4(*(const float4*)(Wc + (r0 + 3) * 256 + 4 * lane), c4);
#pragma unroll
      for (int off = 32; off; off >>= 1) {
        sA += __shfl_xor(sA, off, 64);
        sB += __shfl_xor(sB, off, 64);
        sC += __shfl_xor(sC, off, 64);
        sD += __shfl_xor(sD, off, 64);
      }
      if (lane < 4) {
        int r = r0 + lane;
        float v = (lane == 0) ? sA : (lane == 1) ? sB : (lane == 2) ? sC : sD;
        s_comb[r] = fmaxf(v + bc[r], 0.0f);
      }
    }
  }
  __syncthreads();

  // ---- gates: coalesced quad geometry; dir is wave-uniform ----
  {
    const int dir   = wv >> 2;
    const int gbase = (wv & 3) * 64;
    const float* wih = dir ? wir : wif;
    const float* whh = dir ? whr : whf;
    const float* bih = dir ? bir : bif;
    const float* bhh = dir ? bhr : bhf;
    float4 cm4 = *(const float4*)(&s_comb[4 * gl]);
    float4 h4  = *(const float4*)(&s_h0[dir * H_ + 4 * gl]);
#pragma unroll
    for (int batch = 0; batch < 4; ++batch) {
      const int r0 = gbase + batch * 16;   // 16 gate rows this step
      float sA = dot4(*(const float4*)(wih + (r0 +  0 + grp) * H_ + 4 * gl), cm4)
               + dot4(*(const float4*)(whh + (r0 +  0 + grp) * H_ + 4 * gl), h4);
      float sB = dot4(*(const float4*)(wih + (r0 +  4 + grp) * H_ + 4 * gl), cm4)
               + dot4(*(const float4*)(whh + (r0 +  4 + grp) * H_ + 4 * gl), h4);
      float sC = dot4(*(const float4*)(wih + (r0 +  8 + grp) * H_ + 4 * gl), cm4)
               + dot4(*(const float4*)(whh + (r0 +  8 + grp) * H_ + 4 * gl), h4);
      float sD = dot4(*(const float4*)(wih + (r0 + 12 + grp) * H_ + 4 * gl), cm4)
               + dot4(*(const float4*)(whh + (r0 + 12 + grp) * H_ + 4 * gl), h4);
#pragma unroll
      for (int off = 8; off; off >>= 1) {
        sA += __shfl_xor(sA, off, 64);
        sB += __shfl_xor(sB, off, 64);
        sC += __shfl_xor(sC, off, 64);
        sD += __shfl_xor(sD, off, 64);
      }
      if (gl < 4) {   // lane gl writes value gl for its grp
        int gg = r0 + gl * 4 + grp;
        float v = (gl == 0) ? sA : (gl == 1) ? sB : (gl == 2) ? sC : sD;
        s_gates[dir][gg] = v + bih[gg] + bhh[gg];
      }
    }
  }
  __syncthreads();

  // ---- finalize LSTM + write all three outputs ----
  if (tid < 2 * H_) {
    int dir = tid >> 6, j = tid & 63;
    float gi = s_gates[dir][j];
    float gf = s_gates[dir][H_ + j];
    float gg = s_gates[dir][2 * H_ + j];
    float go = s_gates[dir][3 * H_ + j];
    float cp = c0[dir * B_ * H_ + b * H_ + j];
    float cn = sigm(gf) * cp + sigm(gi) * tanhf(gg);
    float hn = sigm(go) * tanhf(cn);
    out[b * 2 * H_ + dir * H_ + j]                    = hn;  // output (b,1,128)
    out[B_ * 2 * H_ + dir * B_ * H_ + b * H_ + j]     = hn;  // h_new (2,b,64)
    out[2 * B_ * 2 * H_ + dir * B_ * H_ + b * H_ + j] = cn;  // c_new (2,b,64)
  }
}

extern "C" void kernel_launch(void* const* d_in, const int* in_sizes, int n_in,
                              void* d_out, int out_size, void* d_ws, size_t ws_size,
                              hipStream_t stream) {
  const float* h0  = (const float*)d_in[0];
  const float* c0  = (const float*)d_in[1];
  const float* enc = (const float*)d_in[2];
  const float* Wa  = (const float*)d_in[3];
  const float* ba  = (const float*)d_in[4];
  const float* Wc  = (const float*)d_in[5];
  const float* bc  = (const float*)d_in[6];
  const float* wif = (const float*)d_in[7];
  const float* whf = (const float*)d_in[8];
  const float* bif = (const float*)d_in[9];
  const float* bhf = (const float*)d_in[10];
  const float* wir = (const float*)d_in[11];
  const float* whr = (const float*)d_in[12];
  const float* bir = (const float*)d_in[13];
  const float* bhr = (const float*)d_in[14];
  const int*   dip = (const int*)d_in[15];
  float* out = (float*)d_out;

  attn_decoder_fused<<<B_, 512, 0, stream>>>(h0, c0, enc, Wa, ba, Wc, bc,
                                             wif, whf, bif, bhf,
                                             wir, whr, bir, bhr, dip, out);
}